// Round 7
// baseline (3819.138 us; speedup 1.0000x reference)
//
#include <hip/hip_runtime.h>

// Elman ReLU RNN, fused persistent kernel. Round-4 proven structure
// (split-K-4, flag handshake, superstep barriers, readlane xp) run as TWO
// independent batch groups per workgroup so each SIMD hosts two waves of the
// SAME role from DIFFERENT batches: one batch's latency stalls (h-read
// round-trip, handshake spin) are filled by the other batch's FMA issue.
//
// 128 blocks x 512 threads. Group g = tid>>8 handles batch 2*blk+g with its
// own Smem + flags. Waves 0-3 (g0) / 4-7 (g1) -> SIMD (w&3): pairs are
// (hA,hA) (hB,hB) (fc,fc) (xp,xp) per SIMD.
// Within a group (identical to round 4/6):
//   waves 0-1: h-update, split-K-4 (lane: chunk k=ln&3, rows rl+16p, offset
//              58*wv). Chunk-padded h layout (36 floats / 32-chunk). Per
//              step: poll other h-wave's flag >= t-1, read h(t-1)+xp[t],
//              128 FMA, DPP quad-reduce, write h(t), bump flag.
//   wave  2  : fc, lagging one superstep (u in [8s-8, 8s-1], barrier-publ.).
//   wave  3  : xp producer, leading one superstep (tau in [8s+8, 8s+15]);
//              x held in a 4-deep register ring, broadcast via readlane.
// Full (lgkm-only) barrier once per 8 steps, shared by both groups (cheap
// rendezvous; schedules are aligned). Rings: h depth 16, xp depth 16.

namespace {
constexpr int kB = 256;
constexpr int kT = 2048;
constexpr int kI = 50;
constexpr int kH = 116;
constexpr int kO = 50;
constexpr int kSS = 8;    // steps per superstep (barrier period)
constexpr int kHD = 16;   // h ring depth
constexpr int kXPD = 16;  // xp ring depth
constexpr int kG = 2;     // batch groups per workgroup
}

struct Smem {
  // h element e of step t lives at h[t&15][36*(e>>5) + (e&31)] (chunk-padded:
  // chunk k = float4 index 9k; the 4 distinct chunk addresses in one wave
  // instruction hit disjoint bank groups).
  alignas(16) float h[kHD][144];    // 9216 B
  alignas(16) float xp[kXPD][128];  // 8192 B
  int flags[2];                     // per-h-wave completed-step counters
};

__device__ __forceinline__ void sync_lds() {
  // Workgroup barrier draining LDS only; vmcnt stays in flight so the global
  // x prefetch and fc output stores pipeline across supersteps.
  __asm__ __volatile__("s_waitcnt lgkmcnt(0)\n\ts_barrier" ::: "memory");
}

// Quad butterfly adds via DPP quad_perm: VALU-only, no LDS pipe traffic.
__device__ __forceinline__ float qadd1(float v) {  // + lane^1
  return v + __int_as_float(__builtin_amdgcn_update_dpp(
                 0, __float_as_int(v), 0xB1, 0xF, 0xF, true));
}
__device__ __forceinline__ float qadd2(float v) {  // + lane^2
  return v + __int_as_float(__builtin_amdgcn_update_dpp(
                 0, __float_as_int(v), 0x4E, 0xF, 0xF, true));
}

// h-update step t: poll, then read xp[t&15] + h[(t-1)&15], compute, write
// h[t&15], bump own flag. Arithmetic identical to rounds 3/4/6 (bit-identical
// trajectory). Spin cycles are donated to the co-resident group's wave.
__device__ __forceinline__ void h_step(Smem& sm, int t, const float (&w)[4][32],
                                       int k, int rowk, int hwr, bool wvalid,
                                       bool need_poll,
                                       const volatile int* oth,
                                       volatile int* my, int ln) {
  if (need_poll) {
    while (__builtin_amdgcn_readfirstlane(*oth) < t - 1) {}
    __asm__ __volatile__("" ::: "memory");  // h reads stay below the poll
  }
  const float xpv = sm.xp[t & (kXPD - 1)][rowk];
  const float4* hp4 = (const float4*)sm.h[(t + kHD - 1) & (kHD - 1)];
  float4 hc[8];
#pragma unroll
  for (int i = 0; i < 8; ++i) hc[i] = hp4[9 * k + i];
  float res = 0.f;
#pragma unroll
  for (int p = 0; p < 4; ++p) {
    float s0 = 0.f, s1 = 0.f, s2 = 0.f, s3 = 0.f;
#pragma unroll
    for (int i = 0; i < 8; ++i) {
      const float4 v = hc[i];
      s0 = fmaf(w[p][4 * i + 0], v.x, s0);
      s1 = fmaf(w[p][4 * i + 1], v.y, s1);
      s2 = fmaf(w[p][4 * i + 2], v.z, s2);
      s3 = fmaf(w[p][4 * i + 3], v.w, s3);
    }
    float c = (s0 + s1) + (s2 + s3);
    c = qadd2(qadd1(c));  // quad total, bit-identical in all 4 lanes
    res = (k == p) ? c : res;
  }
  res += xpv;
  res = res > 0.f ? res : 0.f;
  if (wvalid) sm.h[t & (kHD - 1)][hwr] = res;
  __asm__ __volatile__("" ::: "memory");  // h-write ordered before flag bump
  if (ln == 0) *my = t;
}

// fc for h[u] (ring slot u&15): split-K-4, global store. Runs only on
// barrier-published slots.
__device__ __forceinline__ void fc_step(Smem& sm, int u, const float (&w)[4][32],
                                        int k, int rowk, float bfc,
                                        float* __restrict__ ob) {
  const float4* hp4 = (const float4*)sm.h[u & (kHD - 1)];
  float4 hc[8];
#pragma unroll
  for (int i = 0; i < 8; ++i) hc[i] = hp4[9 * k + i];
  float res = 0.f;
#pragma unroll
  for (int p = 0; p < 4; ++p) {
    float s0 = 0.f, s1 = 0.f, s2 = 0.f, s3 = 0.f;
#pragma unroll
    for (int i = 0; i < 8; ++i) {
      const float4 v = hc[i];
      s0 = fmaf(w[p][4 * i + 0], v.x, s0);
      s1 = fmaf(w[p][4 * i + 1], v.y, s1);
      s2 = fmaf(w[p][4 * i + 2], v.z, s2);
      s3 = fmaf(w[p][4 * i + 3], v.w, s3);
    }
    float c = (s0 + s1) + (s2 + s3);
    c = qadd2(qadd1(c));
    res = (k == p) ? c : res;
  }
  res += bfc;
  if (rowk < kO) ob[(size_t)u * kO + rowk] = res;
}

// xp step via readlane broadcast: xv holds x[tau][ln] in lanes 0..49.
// Same values, same chain structure (element j -> chain j&3) as the LDS ring.
__device__ __forceinline__ void xp_step_rl(Smem& sm, int slot, float xv,
                                           const float (&wi0)[kI],
                                           const float (&wi1)[kI],
                                           float bias0, float bias1, int ln) {
  const int xvi = __float_as_int(xv);
  float s00 = 0.f, s01 = 0.f, s02 = 0.f, s03 = 0.f;
  float s10 = 0.f, s11 = 0.f, s12 = 0.f, s13 = 0.f;
#pragma unroll
  for (int i = 0; i < 12; ++i) {
    const float x0 = __int_as_float(__builtin_amdgcn_readlane(xvi, 4 * i + 0));
    const float x1 = __int_as_float(__builtin_amdgcn_readlane(xvi, 4 * i + 1));
    const float x2 = __int_as_float(__builtin_amdgcn_readlane(xvi, 4 * i + 2));
    const float x3 = __int_as_float(__builtin_amdgcn_readlane(xvi, 4 * i + 3));
    s00 = fmaf(wi0[4 * i + 0], x0, s00);
    s01 = fmaf(wi0[4 * i + 1], x1, s01);
    s02 = fmaf(wi0[4 * i + 2], x2, s02);
    s03 = fmaf(wi0[4 * i + 3], x3, s03);
    s10 = fmaf(wi1[4 * i + 0], x0, s10);
    s11 = fmaf(wi1[4 * i + 1], x1, s11);
    s12 = fmaf(wi1[4 * i + 2], x2, s12);
    s13 = fmaf(wi1[4 * i + 3], x3, s13);
  }
  const float x48 = __int_as_float(__builtin_amdgcn_readlane(xvi, 48));
  const float x49 = __int_as_float(__builtin_amdgcn_readlane(xvi, 49));
  s00 = fmaf(wi0[48], x48, s00);
  s01 = fmaf(wi0[49], x49, s01);
  s10 = fmaf(wi1[48], x48, s10);
  s11 = fmaf(wi1[49], x49, s11);
  sm.xp[slot][ln] = bias0 + ((s00 + s01) + (s02 + s03));
  if (ln < kH - 64) sm.xp[slot][ln + 64] = bias1 + ((s10 + s11) + (s12 + s13));
}

__launch_bounds__(512, 1)
__global__ void rnn_fused(const float* __restrict__ x,
                          const float* __restrict__ W_ih,
                          const float* __restrict__ b_ih,
                          const float* __restrict__ W_hh,
                          const float* __restrict__ b_hh,
                          const float* __restrict__ W_fc,
                          const float* __restrict__ b_fc,
                          float* __restrict__ out) {
  __shared__ Smem sm2[kG];
  const int tid = threadIdx.x;
  const int grp = tid >> 8;        // batch group within the workgroup
  const int tig = tid & 255;       // tid within group
  const int wv = (tid >> 6) & 3;   // wave role within group
  const int ln = tid & 63;
  Smem& sm = sm2[grp];
  const int b = kG * blockIdx.x + grp;
  const float* xb = x + (size_t)b * (kT * kI);
  float* ob = out + (size_t)b * (kT * kO);

  float w[4][32];          // waves 0-2: per-lane weight tile (chunk k, 4 rows)
  float wi0[kI], wi1[kI];  // wave 3: W_ih rows ln, ln+64
  float bias0 = 0.f, bias1 = 0.f, bfc = 0.f;
  float xrv[4] = {0.f, 0.f, 0.f, 0.f};  // x register ring: xrv[q] = x[tau],
                                        // tau the next step with tau&3 == q

  const int k = ln & 3;    // K-chunk (h columns [32k, 32k+32))
  const int rl = ln >> 2;  // local row 0..15
  int rowk = 0, hwr = 0;   // kept row after quad reduce; padded write index
  bool wvalid = false;

  if (wv < 2) {
    const int rbase = 58 * wv;
    rowk = rbase + rl + 16 * k;
    wvalid = (rl + 16 * k) < 58;
    hwr = 36 * (rowk >> 5) + (rowk & 31);
#pragma unroll
    for (int p = 0; p < 4; ++p) {
      const int rloc = rl + 16 * p;
      const bool vr = rloc < 58;
      const size_t r = rbase + (vr ? rloc : 0);
#pragma unroll
      for (int j = 0; j < 32; ++j) {
        const int col = 32 * k + j;
        w[p][j] = (vr && col < kH) ? W_hh[r * kH + col] : 0.f;
      }
    }
  } else if (wv == 2) {
    rowk = rl + 16 * k;
#pragma unroll
    for (int p = 0; p < 4; ++p) {
      const int rloc = rl + 16 * p;
      const bool vr = rloc < kO;
      const size_t r = vr ? rloc : 0;
#pragma unroll
      for (int j = 0; j < 32; ++j) {
        const int col = 32 * k + j;
        w[p][j] = (vr && col < kH) ? W_fc[r * kH + col] : 0.f;
      }
    }
    bfc = (rowk < kO) ? b_fc[rowk] : 0.f;
  } else {
    {
      const float2* wr = (const float2*)(W_ih + ln * kI);  // 200B rows: 8B aligned
#pragma unroll
      for (int i = 0; i < kI / 2; ++i) {
        float2 v = wr[i]; wi0[2 * i] = v.x; wi0[2 * i + 1] = v.y;
      }
      bias0 = b_ih[ln] + b_hh[ln];
    }
    if (ln < kH - 64) {
      const float2* wr = (const float2*)(W_ih + (ln + 64) * kI);
#pragma unroll
      for (int i = 0; i < kI / 2; ++i) {
        float2 v = wr[i]; wi1[2 * i] = v.x; wi1[2 * i + 1] = v.y;
      }
      bias1 = b_ih[ln + 64] + b_hh[ln + 64];
    } else {
#pragma unroll
      for (int i = 0; i < kI; ++i) wi1[i] = 0.f;
    }
    if (ln < kI) {
#pragma unroll
      for (int q = 0; q < 4; ++q) xrv[q] = xb[(size_t)q * kI + ln];
    }
  }
  // Zero the ENTIRE h ring (per group): h(-1)=0 at slot 15, and all pad
  // positions must stay 0 forever (they multiply zero weights).
  for (int z = tig; z < kHD * 144; z += 256) ((float*)sm.h)[z] = 0.f;
  if (tig == 0) { sm.flags[0] = -1; sm.flags[1] = -1; }
  sync_lds();  // barrier: init published (both groups)

  if (wv < 2) __builtin_amdgcn_s_setprio(1);  // favor the recurrence waves

  // xp prologue: tau = 0..7 fills xp slots 0..7 so h can start at t=0.
  if (wv == 3) {
#pragma unroll
    for (int j = 0; j < kSS; ++j) {
      xp_step_rl(sm, j & (kXPD - 1), xrv[j & 3], wi0, wi1, bias0, bias1, ln);
      if (ln < kI) xrv[j & 3] = xb[(size_t)(j + 4) * kI + ln];  // j+4 <= 11
    }
  }
  sync_lds();  // barrier: xp[0..7] published

  volatile int* my = (volatile int*)&sm.flags[wv & 1];
  const volatile int* oth = (const volatile int*)&sm.flags[1 - (wv & 1)];

#pragma unroll 1
  for (int s = 0; s < kT / kSS; ++s) {
    if (wv < 2) {
      // 8 serial steps; pairwise flag handshake, no per-step barrier.
      const int t0 = kSS * s;
#pragma unroll
      for (int j = 0; j < kSS; ++j)
        h_step(sm, t0 + j, w, k, rowk, hwr, wvalid, j > 0, oth, my, ln);
    } else if (wv == 2) {
      // Lag one superstep: u in [8s-8, 8s-1]; all h[u] barrier-published.
      if (s > 0) {
        const int u0 = kSS * (s - 1);
#pragma unroll
        for (int j = 0; j < kSS; ++j)
          fc_step(sm, u0 + j, w, k, rowk, bfc, ob);
      }
    } else {
      // Lead one superstep: tau in [8s+8, 8s+15]; slots disjoint (mod 16)
      // from the h-waves' reads this superstep. tau0 % 4 == 0 -> tau&3 == j&3.
      if (s < kT / kSS - 1) {
        const int tau0 = kSS * s + kSS;
#pragma unroll
        for (int j = 0; j < kSS; ++j) {
          const int tau = tau0 + j;
          xp_step_rl(sm, tau & (kXPD - 1), xrv[j & 3], wi0, wi1, bias0, bias1,
                     ln);
          if (ln < kI) {
            int tf = tau + 4; tf = tf < kT ? tf : kT - 1;
            xrv[j & 3] = xb[(size_t)tf * kI + ln];
          }
        }
      }
    }
    sync_lds();  // one barrier per 8 steps (8-wave rendezvous, both groups)
  }

  // fc epilogue: u = 2040..2047 (published by the final barrier).
  if (wv == 2) {
#pragma unroll
    for (int j = 0; j < kSS; ++j)
      fc_step(sm, kT - kSS + j, w, k, rowk, bfc, ob);
  }
}

extern "C" void kernel_launch(void* const* d_in, const int* in_sizes, int n_in,
                              void* d_out, int out_size, void* d_ws, size_t ws_size,
                              hipStream_t stream) {
  (void)in_sizes; (void)n_in; (void)d_ws; (void)ws_size; (void)out_size;
  const float* x    = (const float*)d_in[0];
  const float* W_ih = (const float*)d_in[1];
  const float* b_ih = (const float*)d_in[2];
  const float* W_hh = (const float*)d_in[3];
  const float* b_hh = (const float*)d_in[4];
  const float* W_fc = (const float*)d_in[5];
  const float* b_fc = (const float*)d_in[6];
  float* out = (float*)d_out;
  rnn_fused<<<dim3(kB / kG), dim3(512), 0, stream>>>(x, W_ih, b_ih, W_hh, b_hh,
                                                     W_fc, b_fc, out);
}